// Round 8
// baseline (5495.198 us; speedup 1.0000x reference)
//
#include <hip/hip_runtime.h>

#define D 64
#define EPT 16    // edges per thread in partition
#define EPTC 32   // edges per thread in count
#define BKT 128   // nodes per bucket (32KB LDS tile)
#define KMAX 2048

// ---- bf16 helpers ----
static __device__ __forceinline__ unsigned short f2bf(float f) {
    unsigned int u = __float_as_uint(f);
    unsigned int r = (u + 0x7FFFu + ((u >> 16) & 1u)) >> 16;
    return (unsigned short)r;
}
static __device__ __forceinline__ float bflo(unsigned int u) {
    return __uint_as_float(u << 16);
}
static __device__ __forceinline__ float bfhi(unsigned int u) {
    return __uint_as_float(u & 0xFFFF0000u);
}

// ---------------- init: fp32 acc + bf16 cur ----------------
__global__ void init_kernel(const float4* __restrict__ user_w,
                            const float4* __restrict__ item_w,
                            float4* __restrict__ acc,
                            ushort4* __restrict__ curb,
                            int n_user4, int n_tot4) {
    int i = blockIdx.x * blockDim.x + threadIdx.x;
    if (i >= n_tot4) return;
    float4 v = (i < n_user4) ? user_w[i] : item_w[i - n_user4];
    acc[i] = v;
    ushort4 b;
    b.x = f2bf(v.x); b.y = f2bf(v.y); b.z = f2bf(v.z); b.w = f2bf(v.w);
    curb[i] = b;
}

// ---------------- bucket counts ----------------
__global__ void count_kernel(const int* __restrict__ dst,
                             int* __restrict__ bkt_cnt, int K_, int E_) {
    __shared__ int cnt[KMAX];
    for (int k = threadIdx.x; k < K_; k += 256) cnt[k] = 0;
    __syncthreads();
    int b0 = blockIdx.x * (256 * EPTC);
#pragma unroll 4
    for (int e = 0; e < EPTC; ++e) {
        int i = b0 + e * 256 + threadIdx.x;
        if (i < E_) atomicAdd(&cnt[dst[i] / BKT], 1);
    }
    __syncthreads();
    for (int k = threadIdx.x; k < K_; k += 256) {
        int c = cnt[k];
        if (c) atomicAdd(&bkt_cnt[k], c);
    }
}

// single block, 1024 threads, 2 elems/thread: exclusive scan of K<=2048 counts.
__global__ void scan_bkt_kernel(const int* __restrict__ cnt,
                                int* __restrict__ base,
                                int* __restrict__ gpos, int K_, int E_) {
    __shared__ int sh[1024];
    int t = threadIdx.x;
    int i0 = 2 * t, i1 = 2 * t + 1;
    int c0 = (i0 < K_) ? cnt[i0] : 0;
    int c1 = (i1 < K_) ? cnt[i1] : 0;
    sh[t] = c0 + c1;
    __syncthreads();
    for (int off = 1; off < 1024; off <<= 1) {
        int v = (t >= off) ? sh[t - off] : 0;
        __syncthreads();
        sh[t] += v;
        __syncthreads();
    }
    int excl = sh[t] - (c0 + c1);
    if (i0 < K_) { base[i0] = excl; gpos[i0] = excl; }
    if (i1 < K_) { base[i1] = excl + c0; gpos[i1] = excl + c0; }
    if (t == 0) base[K_] = E_;
}

// partition: LDS histogram + LDS ranks; ONE global atomic per (block,bucket).
// st entry: {src, (val_bf16<<16) | dst_off7}. Runs are bucket-contiguous.
__global__ void partition_kernel(const int* __restrict__ src,
                                 const int* __restrict__ dst,
                                 const float* __restrict__ val,
                                 int* __restrict__ g_pos,
                                 int2* __restrict__ st,
                                 int K_, int E_) {
    __shared__ int cnt[KMAX];
    __shared__ int base[KMAX];
    for (int k = threadIdx.x; k < K_; k += 256) cnt[k] = 0;
    __syncthreads();
    int b0 = blockIdx.x * (256 * EPT);
    int myk[EPT], myr[EPT], mysrc[EPT];
    unsigned mypk[EPT];
#pragma unroll
    for (int e = 0; e < EPT; ++e) {
        int i = b0 + e * 256 + threadIdx.x;
        if (i < E_) {
            int d = dst[i];
            int k = d / BKT;
            myk[e] = k;
            mysrc[e] = src[i];
            mypk[e] = ((unsigned)f2bf(val[i]) << 16) | (unsigned)(d & (BKT - 1));
            myr[e] = atomicAdd(&cnt[k], 1);
        } else {
            myk[e] = -1;
        }
    }
    __syncthreads();
    for (int k = threadIdx.x; k < K_; k += 256) {
        int c = cnt[k];
        base[k] = c ? atomicAdd(&g_pos[k], c) : 0;
    }
    __syncthreads();
#pragma unroll
    for (int e = 0; e < EPT; ++e) {
        if (myk[e] >= 0)
            st[base[myk[e]] + myr[e]] = make_int2(mysrc[e], (int)mypk[e]);
    }
}

// ---------------- SpMM: bucket-tile LDS accumulate ----------------
// One block per 128-node bucket; 32KB fp32 tile in LDS; edges unordered within
// the bucket. Half-wave per edge: 2 shfl broadcasts, 128B bf16 row gather,
// LDS float atomicAdd (2-way bank alias = free). Writeout streams the tile.
__global__ __launch_bounds__(256)
void spmm_lds_kernel(const int2* __restrict__ st,
                     const int* __restrict__ bkt_base,
                     const ushort2* __restrict__ xb,
                     uint2* __restrict__ nxtb,
                     float4* __restrict__ acc,
                     int N_, int write_nxt) {
    __shared__ float facc[BKT * D];
    int b = blockIdx.x;
    int tid = threadIdx.x;
    float4* f4 = (float4*)facc;
    for (int i = tid; i < BKT * D / 4; i += 256)
        f4[i] = make_float4(0.f, 0.f, 0.f, 0.f);
    __syncthreads();
    int beg = bkt_base[b];
    int end = bkt_base[b + 1];
    int lane = tid & 63;
    int wave = tid >> 6;
    int half = lane >> 5;
    int lid = lane & 31;
    for (int base = beg + wave * 64; base < end; base += 256) {
        int e = base + lane;
        int c = 0;
        unsigned pk = 0;
        if (e < end) {
            int2 cv = st[e];
            c = cv.x;
            pk = (unsigned)cv.y;
        }
        int m = min(64, end - base);
        int m2 = (m + 1) & ~1;
        for (int j = 0; j < m2; j += 2) {
            int cj = __shfl(c, j + half, 64);
            unsigned pkj = (unsigned)__shfl((int)pk, j + half, 64);
            float vj = bfhi(pkj);
            int off = (int)(pkj & (BKT - 1));
            ushort2 q = xb[(long)cj * 32 + lid];
            float* dp = &facc[off * D + lid * 2];
            atomicAdd(dp, vj * __uint_as_float((unsigned)q.x << 16));
            atomicAdd(dp + 1, vj * __uint_as_float((unsigned)q.y << 16));
        }
    }
    __syncthreads();
    // writeout: 128 rows x 16 float4
    long gbase = (long)b * (BKT * D / 4);
    for (int i = tid; i < BKT * D / 4; i += 256) {
        int row = (b << 7) + (i >> 4);
        if (row < N_) {
            float4 v = f4[i];
            float4 a = acc[gbase + i];
            a.x += v.x; a.y += v.y; a.z += v.z; a.w += v.w;
            acc[gbase + i] = a;
            if (write_nxt) {
                uint2 o;
                o.x = (unsigned)f2bf(v.x) | ((unsigned)f2bf(v.y) << 16);
                o.y = (unsigned)f2bf(v.z) | ((unsigned)f2bf(v.w) << 16);
                nxtb[gbase + i] = o;
            }
        }
    }
}

// ---------------- epilogue ----------------
__global__ void final_kernel(const float* __restrict__ acc,
                             const float* __restrict__ user_w,
                             const float* __restrict__ item_w,
                             const int* __restrict__ bu,
                             const int* __restrict__ bp,
                             const int* __restrict__ bn,
                             float* __restrict__ out,
                             float* __restrict__ red,
                             int U_, int B_) {
    __shared__ float pr[4];
    int w = (int)((blockIdx.x * blockDim.x + threadIdx.x) >> 6);
    int lane = threadIdx.x & 63;
    bool valid = (w < B_);
    float ps = 0.f, ns = 0.f, r = 0.f;
    if (valid) {
        int iu = bu[w], ip = bp[w], in_ = bn[w];
        const float scale = 0.25f;  // 1/(L+1)
        float u = acc[(long)iu * D + lane] * scale;
        float p = acc[(long)(U_ + ip) * D + lane] * scale;
        float g = acc[(long)(U_ + in_) * D + lane] * scale;
        ps = u * p;
        ns = u * g;
        float u0 = user_w[(long)iu * D + lane];
        float p0 = item_w[(long)ip * D + lane];
        float n0 = item_w[(long)in_ * D + lane];
        r = u0 * u0 + p0 * p0 + n0 * n0;
    }
#pragma unroll
    for (int off = 32; off; off >>= 1) {
        ps += __shfl_down(ps, off, 64);
        ns += __shfl_down(ns, off, 64);
        r  += __shfl_down(r, off, 64);
    }
    if (lane == 0) pr[threadIdx.x >> 6] = r;
    __syncthreads();
    if (threadIdx.x == 0)
        red[blockIdx.x] = pr[0] + pr[1] + pr[2] + pr[3];
    if (valid && lane == 0) {
        out[w] = ps;
        out[B_ + w] = ns;
    }
}

__global__ void reduce_kernel(const float* __restrict__ red,
                              float* __restrict__ out_scalar, int nblk) {
    __shared__ float sh[256];
    float s = 0.f;
    for (int i = threadIdx.x; i < nblk; i += 256) s += red[i];
    sh[threadIdx.x] = s;
    __syncthreads();
    for (int off = 128; off; off >>= 1) {
        if (threadIdx.x < off) sh[threadIdx.x] += sh[threadIdx.x + off];
        __syncthreads();
    }
    if (threadIdx.x == 0) *out_scalar = sh[0];
}

// ---------------- launch ----------------
extern "C" void kernel_launch(void* const* d_in, const int* in_sizes, int n_in,
                              void* d_out, int out_size, void* d_ws, size_t ws_size,
                              hipStream_t stream) {
    const int*   edge_src = (const int*)d_in[0];
    const int*   edge_dst = (const int*)d_in[1];
    const float* edge_val = (const float*)d_in[2];
    const float* user_w   = (const float*)d_in[3];
    const float* item_w   = (const float*)d_in[4];
    const int*   bu       = (const int*)d_in[5];
    const int*   bp       = (const int*)d_in[6];
    const int*   bn       = (const int*)d_in[7];

    int E_ = in_sizes[0];
    int U_ = in_sizes[3] / D;
    int I_ = in_sizes[4] / D;
    int B_ = in_sizes[5];
    int N_ = U_ + I_;
    long ND = (long)N_ * D;
    int K_ = (N_ + BKT - 1) / BKT;   // <= KMAX assumed (N <= 262144)

    // ---- workspace layout ----
    char* p = (char*)d_ws;
    int2* st       = (int2*)p;       p += (size_t)E_ * sizeof(int2);
    int*  bkt_cnt  = (int*)p;        p += KMAX * sizeof(int);
    int*  bkt_base = (int*)p;        p += (KMAX + 1) * sizeof(int);
    int*  g_pos    = (int*)p;        p += KMAX * sizeof(int);
    float* red     = (float*)p;      p += 4096 * sizeof(float);
    p = (char*)(((uintptr_t)p + 255) & ~(uintptr_t)255);
    float* acc = (float*)p;
    unsigned short* curb = (unsigned short*)(acc + ND);
    unsigned short* nxtb = curb + ND;
    float* out = (float*)d_out;

    int n4 = (int)(ND / 4);
    int nu4 = U_ * D / 4;

    // ---- build ----
    hipMemsetAsync(bkt_cnt, 0, KMAX * sizeof(int), stream);
    count_kernel<<<(E_ + 256 * EPTC - 1) / (256 * EPTC), 256, 0, stream>>>(
        edge_dst, bkt_cnt, K_, E_);
    scan_bkt_kernel<<<1, 1024, 0, stream>>>(bkt_cnt, bkt_base, g_pos, K_, E_);
    partition_kernel<<<(E_ + 256 * EPT - 1) / (256 * EPT), 256, 0, stream>>>(
        edge_src, edge_dst, edge_val, g_pos, st, K_, E_);

    init_kernel<<<(n4 + 255) / 256, 256, 0, stream>>>(
        (const float4*)user_w, (const float4*)item_w,
        (float4*)acc, (ushort4*)curb, nu4, n4);

    // ---- propagation ----
    unsigned short* cb = curb;
    unsigned short* nb = nxtb;
    for (int l = 0; l < 3; ++l) {
        spmm_lds_kernel<<<K_, 256, 0, stream>>>(
            st, bkt_base, (const ushort2*)cb, (uint2*)nb, (float4*)acc,
            N_, (l < 2) ? 1 : 0);
        unsigned short* t = cb; cb = nb; nb = t;
    }

    // ---- epilogue ----
    int nblk = (B_ * 64 + 255) / 256;
    final_kernel<<<nblk, 256, 0, stream>>>(
        acc, user_w, item_w, bu, bp, bn, out, red, U_, B_);
    reduce_kernel<<<1, 256, 0, stream>>>(red, out + 2 * B_, nblk);
}

// Round 9
// 593.337 us; speedup vs baseline: 9.2615x; 9.2615x over previous
//
#include <hip/hip_runtime.h>

#define D 64
#define EPT 16    // edges per thread in partition
#define EPTC 32   // edges per thread in count
#define BKT 256   // nodes per bucket
#define KMAX 1024

// ---- bf16 helpers ----
static __device__ __forceinline__ unsigned short f2bf(float f) {
    unsigned int u = __float_as_uint(f);
    unsigned int r = (u + 0x7FFFu + ((u >> 16) & 1u)) >> 16;
    return (unsigned short)r;
}
static __device__ __forceinline__ float bflo(unsigned int u) {
    return __uint_as_float(u << 16);
}
static __device__ __forceinline__ float bfhi(unsigned int u) {
    return __uint_as_float(u & 0xFFFF0000u);
}

// ---------------- init: bf16 cur only (acc seeded by spmm layer 0) ----------
__global__ void init_kernel(const float4* __restrict__ user_w,
                            const float4* __restrict__ item_w,
                            ushort4* __restrict__ curb,
                            int n_user4, int n_tot4) {
    int i = blockIdx.x * blockDim.x + threadIdx.x;
    if (i >= n_tot4) return;
    float4 v = (i < n_user4) ? user_w[i] : item_w[i - n_user4];
    ushort4 b;
    b.x = f2bf(v.x); b.y = f2bf(v.y); b.z = f2bf(v.z); b.w = f2bf(v.w);
    curb[i] = b;
}

// ---------------- bucket counts ----------------
// LDS histogram over K buckets; ONE global atomic per (block,bucket).
__global__ void count_kernel(const int* __restrict__ dst,
                             int* __restrict__ bkt_cnt, int K_, int E_) {
    __shared__ int cnt[KMAX];
    for (int k = threadIdx.x; k < K_; k += 256) cnt[k] = 0;
    __syncthreads();
    int b0 = blockIdx.x * (256 * EPTC);
#pragma unroll 4
    for (int e = 0; e < EPTC; ++e) {
        int i = b0 + e * 256 + threadIdx.x;
        if (i < E_) atomicAdd(&cnt[dst[i] >> 8], 1);
    }
    __syncthreads();
    for (int k = threadIdx.x; k < K_; k += 256) {
        int c = cnt[k];
        if (c) atomicAdd(&bkt_cnt[k], c);
    }
}

// single block, 1024 threads, 2 elems/thread: exclusive scan of K<=2048 counts.
__global__ void scan_bkt_kernel(const int* __restrict__ cnt,
                                int* __restrict__ base,
                                int* __restrict__ gpos, int K_, int E_) {
    __shared__ int sh[1024];
    int t = threadIdx.x;
    int i0 = 2 * t, i1 = 2 * t + 1;
    int c0 = (i0 < K_) ? cnt[i0] : 0;
    int c1 = (i1 < K_) ? cnt[i1] : 0;
    sh[t] = c0 + c1;
    __syncthreads();
    for (int off = 1; off < 1024; off <<= 1) {
        int v = (t >= off) ? sh[t - off] : 0;
        __syncthreads();
        sh[t] += v;
        __syncthreads();
    }
    int excl = sh[t] - (c0 + c1);
    if (i0 < K_) { base[i0] = excl; gpos[i0] = excl; }
    if (i1 < K_) { base[i1] = excl + c0; gpos[i1] = excl + c0; }
    if (t == 0) base[K_] = E_;
}

// partition: LDS histogram + LDS ranks; ONE global atomic per (block,bucket).
// st entry: {src, (val_bf16<<16) | dst_off8}. Runs are bucket-contiguous.
__global__ void partition_kernel(const int* __restrict__ src,
                                 const int* __restrict__ dst,
                                 const float* __restrict__ val,
                                 int* __restrict__ g_pos,
                                 int2* __restrict__ st,
                                 int K_, int E_) {
    __shared__ int cnt[KMAX];
    __shared__ int base[KMAX];
    for (int k = threadIdx.x; k < K_; k += 256) cnt[k] = 0;
    __syncthreads();
    int b0 = blockIdx.x * (256 * EPT);
    int myk[EPT], myr[EPT], mysrc[EPT];
    unsigned mypk[EPT];
#pragma unroll
    for (int e = 0; e < EPT; ++e) {
        int i = b0 + e * 256 + threadIdx.x;
        if (i < E_) {
            int d = dst[i];
            int k = d >> 8;
            myk[e] = k;
            mysrc[e] = src[i];
            mypk[e] = ((unsigned)f2bf(val[i]) << 16) | (unsigned)(d & (BKT - 1));
            myr[e] = atomicAdd(&cnt[k], 1);
        } else {
            myk[e] = -1;
        }
    }
    __syncthreads();
    for (int k = threadIdx.x; k < K_; k += 256) {
        int c = cnt[k];
        base[k] = c ? atomicAdd(&g_pos[k], c) : 0;
    }
    __syncthreads();
#pragma unroll
    for (int e = 0; e < EPT; ++e) {
        if (myk[e] >= 0)
            st[base[myk[e]] + myr[e]] = make_int2(mysrc[e], (int)mypk[e]);
    }
}

// place: one block per 256-node bucket (K=586 blocks -> ~2.3/CU balance);
// derives local degrees + row_ptr in LDS, then scatters into this bucket's
// L2-resident col_val window. Per-edge atomics are LDS-only.
__global__ void place_kernel(const int2* __restrict__ st,
                             const int* __restrict__ bkt_base,
                             int* __restrict__ row_ptr,
                             int2* __restrict__ col_val,
                             int K_, int N_, int E_) {
    __shared__ int ldeg[BKT];
    __shared__ int sh[BKT];
    __shared__ int lcur[BKT];
    int b = blockIdx.x;
    int tid = threadIdx.x;
    int rbeg = b << 8;
    int beg = bkt_base[b];
    int end = bkt_base[b + 1];
    if (tid < BKT) ldeg[tid] = 0;
    __syncthreads();
    for (int e = beg + tid; e < end; e += 512)
        atomicAdd(&ldeg[(unsigned)st[e].y & (BKT - 1)], 1);
    __syncthreads();
    int v = 0;
    if (tid < BKT) {
        v = ldeg[tid];
        sh[tid] = v;
    }
    __syncthreads();
    for (int off = 1; off < BKT; off <<= 1) {
        int t = 0;
        if (tid < BKT && tid >= off) t = sh[tid - off];
        __syncthreads();
        if (tid < BKT) sh[tid] += t;
        __syncthreads();
    }
    if (tid < BKT) {
        int excl = sh[tid] - v;
        lcur[tid] = excl;
        int gi = rbeg + tid;
        if (gi < N_) row_ptr[gi] = beg + excl;
    }
    if (b == K_ - 1 && tid == 0) row_ptr[N_] = E_;
    __syncthreads();
    for (int e = beg + tid; e < end; e += 512) {
        int2 cv = st[e];
        int p = beg + atomicAdd(&lcur[(unsigned)cv.y & (BKT - 1)], 1);
        col_val[p] = cv;
    }
}

// ---------------- CSR gather SpMM, bf16 rows, 16B/lane loads ----------------
// flags: bit0 = write nxt, bit1 = first layer (acc-in comes from raw weights)
__global__ void spmm_csr_kernel(const int* __restrict__ row_ptr,
                                const int2* __restrict__ col_val,
                                const uint4* __restrict__ xb,
                                uint4* __restrict__ nxtb,
                                float4* __restrict__ acc,
                                const float4* __restrict__ uw,
                                const float4* __restrict__ iw,
                                int U_, int N_, int flags) {
    int row = (int)((blockIdx.x * blockDim.x + threadIdx.x) >> 6);
    int lane = threadIdx.x & 63;
    if (row >= N_) return;
    int q = lane >> 3;    // which of 8 edges in the group
    int lid = lane & 7;   // which 16B chunk of the row
    int beg = row_ptr[row];
    int end = row_ptr[row + 1];
    float s0 = 0, s1 = 0, s2 = 0, s3 = 0, s4 = 0, s5 = 0, s6 = 0, s7 = 0;
    for (int base = beg; base < end; base += 64) {
        int e = base + lane;
        int c = 0;
        float v = 0.f;
        if (e < end) {
            int2 cv = col_val[e];
            c = cv.x;
            v = bfhi((unsigned)cv.y);   // val in high 16 bits
        }
        int m = min(64, end - base);
        int m8 = (m + 7) & ~7;
        for (int j = 0; j < m8; j += 8) {
            int cj = __shfl(c, j + q, 64);
            float vj = __shfl(v, j + q, 64);
            uint4 t = xb[(long)cj * 8 + lid];
            s0 += vj * bflo(t.x); s1 += vj * bfhi(t.x);
            s2 += vj * bflo(t.y); s3 += vj * bfhi(t.y);
            s4 += vj * bflo(t.z); s5 += vj * bfhi(t.z);
            s6 += vj * bflo(t.w); s7 += vj * bfhi(t.w);
        }
    }
#pragma unroll
    for (int off = 32; off >= 8; off >>= 1) {
        s0 += __shfl_xor(s0, off, 64);
        s1 += __shfl_xor(s1, off, 64);
        s2 += __shfl_xor(s2, off, 64);
        s3 += __shfl_xor(s3, off, 64);
        s4 += __shfl_xor(s4, off, 64);
        s5 += __shfl_xor(s5, off, 64);
        s6 += __shfl_xor(s6, off, 64);
        s7 += __shfl_xor(s7, off, 64);
    }
    if (q == 0) {
        if (flags & 1) {
            uint4 b;
            b.x = (unsigned)f2bf(s0) | ((unsigned)f2bf(s1) << 16);
            b.y = (unsigned)f2bf(s2) | ((unsigned)f2bf(s3) << 16);
            b.z = (unsigned)f2bf(s4) | ((unsigned)f2bf(s5) << 16);
            b.w = (unsigned)f2bf(s6) | ((unsigned)f2bf(s7) << 16);
            nxtb[(long)row * 8 + lid] = b;
        }
        float4* ap = acc + (long)row * 16 + lid * 2;
        float4 a0, a1;
        if (flags & 2) {
            const float4* wp = (row < U_) ? (uw + (long)row * 16 + lid * 2)
                                          : (iw + (long)(row - U_) * 16 + lid * 2);
            a0 = wp[0];
            a1 = wp[1];
        } else {
            a0 = ap[0];
            a1 = ap[1];
        }
        a0.x += s0; a0.y += s1; a0.z += s2; a0.w += s3;
        ap[0] = a0;
        a1.x += s4; a1.y += s5; a1.z += s6; a1.w += s7;
        ap[1] = a1;
    }
}

// ---------------- epilogue ----------------
__global__ void final_kernel(const float* __restrict__ acc,
                             const float* __restrict__ user_w,
                             const float* __restrict__ item_w,
                             const int* __restrict__ bu,
                             const int* __restrict__ bp,
                             const int* __restrict__ bn,
                             float* __restrict__ out,
                             float* __restrict__ red,
                             int U_, int B_) {
    __shared__ float pr[4];
    int w = (int)((blockIdx.x * blockDim.x + threadIdx.x) >> 6);
    int lane = threadIdx.x & 63;
    bool valid = (w < B_);
    float ps = 0.f, ns = 0.f, r = 0.f;
    if (valid) {
        int iu = bu[w], ip = bp[w], in_ = bn[w];
        const float scale = 0.25f;  // 1/(L+1)
        float u = acc[(long)iu * D + lane] * scale;
        float p = acc[(long)(U_ + ip) * D + lane] * scale;
        float g = acc[(long)(U_ + in_) * D + lane] * scale;
        ps = u * p;
        ns = u * g;
        float u0 = user_w[(long)iu * D + lane];
        float p0 = item_w[(long)ip * D + lane];
        float n0 = item_w[(long)in_ * D + lane];
        r = u0 * u0 + p0 * p0 + n0 * n0;
    }
#pragma unroll
    for (int off = 32; off; off >>= 1) {
        ps += __shfl_down(ps, off, 64);
        ns += __shfl_down(ns, off, 64);
        r  += __shfl_down(r, off, 64);
    }
    if (lane == 0) pr[threadIdx.x >> 6] = r;
    __syncthreads();
    if (threadIdx.x == 0)
        red[blockIdx.x] = pr[0] + pr[1] + pr[2] + pr[3];
    if (valid && lane == 0) {
        out[w] = ps;
        out[B_ + w] = ns;
    }
}

__global__ void reduce_kernel(const float* __restrict__ red,
                              float* __restrict__ out_scalar, int nblk) {
    __shared__ float sh[256];
    float s = 0.f;
    for (int i = threadIdx.x; i < nblk; i += 256) s += red[i];
    sh[threadIdx.x] = s;
    __syncthreads();
    for (int off = 128; off; off >>= 1) {
        if (threadIdx.x < off) sh[threadIdx.x] += sh[threadIdx.x + off];
        __syncthreads();
    }
    if (threadIdx.x == 0) *out_scalar = sh[0];
}

// ---------------- launch ----------------
extern "C" void kernel_launch(void* const* d_in, const int* in_sizes, int n_in,
                              void* d_out, int out_size, void* d_ws, size_t ws_size,
                              hipStream_t stream) {
    const int*   edge_src = (const int*)d_in[0];
    const int*   edge_dst = (const int*)d_in[1];
    const float* edge_val = (const float*)d_in[2];
    const float* user_w   = (const float*)d_in[3];
    const float* item_w   = (const float*)d_in[4];
    const int*   bu       = (const int*)d_in[5];
    const int*   bp       = (const int*)d_in[6];
    const int*   bn       = (const int*)d_in[7];

    int E_ = in_sizes[0];
    int U_ = in_sizes[3] / D;
    int I_ = in_sizes[4] / D;
    int B_ = in_sizes[5];
    int N_ = U_ + I_;
    long ND = (long)N_ * D;
    int K_ = (N_ + BKT - 1) / BKT;   // <= KMAX assumed (N <= 262144)

    // ---- workspace layout ----
    char* p = (char*)d_ws;
    int2* col_val  = (int2*)p;       p += (size_t)E_ * sizeof(int2);
    int*  row_ptr  = (int*)p;        p += (size_t)(N_ + 1) * sizeof(int);
    int*  bkt_cnt  = (int*)p;        p += KMAX * sizeof(int);
    int*  bkt_base = (int*)p;        p += (KMAX + 1) * sizeof(int);
    int*  g_pos    = (int*)p;        p += KMAX * sizeof(int);
    float* red     = (float*)p;      p += 4096 * sizeof(float);
    p = (char*)(((uintptr_t)p + 255) & ~(uintptr_t)255);
    // overlay: staged edges (build phase) then acc (written first by spmm l0,
    // after place has fully consumed st — stream-ordered)
    int2* st = (int2*)p;
    float* acc = (float*)p;
    unsigned short* curb = (unsigned short*)(acc + ND);
    unsigned short* nxtb = curb + ND;
    float* out = (float*)d_out;

    int n4 = (int)(ND / 4);
    int nu4 = U_ * D / 4;

    // ---- build ----
    hipMemsetAsync(bkt_cnt, 0, KMAX * sizeof(int), stream);
    count_kernel<<<(E_ + 256 * EPTC - 1) / (256 * EPTC), 256, 0, stream>>>(
        edge_dst, bkt_cnt, K_, E_);
    scan_bkt_kernel<<<1, 1024, 0, stream>>>(bkt_cnt, bkt_base, g_pos, K_, E_);
    partition_kernel<<<(E_ + 256 * EPT - 1) / (256 * EPT), 256, 0, stream>>>(
        edge_src, edge_dst, edge_val, g_pos, st, K_, E_);
    place_kernel<<<K_, 512, 0, stream>>>(st, bkt_base, row_ptr, col_val,
                                         K_, N_, E_);

    init_kernel<<<(n4 + 255) / 256, 256, 0, stream>>>(
        (const float4*)user_w, (const float4*)item_w,
        (ushort4*)curb, nu4, n4);

    // ---- propagation ----
    unsigned short* cb = curb;
    unsigned short* nb = nxtb;
    for (int l = 0; l < 3; ++l) {
        int flags = ((l < 2) ? 1 : 0) | ((l == 0) ? 2 : 0);
        spmm_csr_kernel<<<(N_ + 3) / 4, 256, 0, stream>>>(
            row_ptr, col_val, (const uint4*)cb, (uint4*)nb, (float4*)acc,
            (const float4*)user_w, (const float4*)item_w, U_, N_, flags);
        unsigned short* t = cb; cb = nb; nb = t;
    }

    // ---- epilogue ----
    int nblk = (B_ * 64 + 255) / 256;
    final_kernel<<<nblk, 256, 0, stream>>>(
        acc, user_w, item_w, bu, bp, bn, out, red, U_, B_);
    reduce_kernel<<<1, 256, 0, stream>>>(red, out + 2 * B_, nblk);
}